// Round 1
// baseline (383.311 us; speedup 1.0000x reference)
//
#include <hip/hip_runtime.h>

#define LOGZERO -4290774016.0f   // -(65504^2), exactly representable in fp32

constexpr int Bb = 32, Tt = 512, Dd = 512, Vv = 4096;
constexpr int BT = Bb * Tt;

typedef __attribute__((ext_vector_type(8))) short short8;
typedef __attribute__((ext_vector_type(4))) float f32x4;

__device__ __forceinline__ unsigned short f2bf(float f) {
  unsigned int u = __float_as_uint(f);
  u += 0x7FFFu + ((u >> 16) & 1u);   // RNE
  return (unsigned short)(u >> 16);
}

__device__ __forceinline__ float lgadd(float a, float b) {
  float mx = fmaxf(a, b);
  float d  = fabsf(a - b);
  return mx + __logf(1.0f + __expf(-d));
}

// ---- W fp32 -> bf16 ----
__global__ __launch_bounds__(256) void kWconv(const float* __restrict__ W,
                                              unsigned short* __restrict__ Wb) {
  int i = (blockIdx.x * 256 + threadIdx.x) * 4;
  float4 v = *(const float4*)(W + i);
  ushort4 h;
  h.x = f2bf(v.x); h.y = f2bf(v.y); h.z = f2bf(v.z); h.w = f2bf(v.w);
  *(ushort4*)(Wb + i) = h;
}

// ---- fused GEMM + sum(exp(logit)) row stats ----
// grid: 512 blocks = (BT/64 row tiles) x 2 V-halves. 256 threads = 4 waves.
// wave w covers cols [vs*256 + w*64, +64) as 4 col-tiles, rows 0..63 as 4 row-tiles.
__global__ __launch_bounds__(256) void kA(const float* __restrict__ x,
                                          const unsigned short* __restrict__ Wb,
                                          const float* __restrict__ bias,
                                          float* __restrict__ Ssum) {
  __shared__ unsigned short Ald[64 * 512];   // exactly 64 KB, xor-swizzled 16B groups
  const int tid = threadIdx.x;
  const int tile = blockIdx.x >> 1;
  const int vhalf = blockIdx.x & 1;
  const int row0 = tile * 64;

  {  // stage x tile -> bf16 LDS
    const float4* xp = (const float4*)(x + (size_t)row0 * Dd);
    #pragma unroll
    for (int j = 0; j < 32; ++j) {
      int f4 = tid + j * 256;          // 0..8191
      int r = f4 >> 7, c4 = f4 & 127;
      float4 v = xp[f4];
      ushort4 h;
      h.x = f2bf(v.x); h.y = f2bf(v.y); h.z = f2bf(v.z); h.w = f2bf(v.w);
      int idx = r * 512 + (((c4 >> 1) ^ (r & 7)) << 3) + ((c4 & 1) << 2);
      *(ushort4*)&Ald[idx] = h;
    }
  }
  __syncthreads();

  const int lane = tid & 63, w = tid >> 6;
  const int ln15 = lane & 15, quad = lane >> 4;
  float S[4][4];
  #pragma unroll
  for (int rt = 0; rt < 4; ++rt)
    #pragma unroll
    for (int r = 0; r < 4; ++r) S[rt][r] = 0.0f;

  for (int vs = 0; vs < 8; ++vs) {
    const int vbase = vhalf * 2048 + vs * 256 + w * 64;
    f32x4 acc[4][4];
    #pragma unroll
    for (int ct = 0; ct < 4; ++ct)
      #pragma unroll
      for (int rt = 0; rt < 4; ++rt) acc[ct][rt] = {0.f, 0.f, 0.f, 0.f};

    #pragma unroll 2
    for (int k = 0; k < Dd; k += 32) {
      short8 afr[4];
      #pragma unroll
      for (int rt = 0; rt < 4; ++rt) {
        int row = rt * 16 + ln15;
        int idx = row * 512 + ((((k >> 3) + quad) ^ (row & 7)) << 3);
        afr[rt] = *(const short8*)&Ald[idx];
      }
      #pragma unroll
      for (int ct = 0; ct < 4; ++ct) {
        int v = vbase + ct * 16 + ln15;
        short8 bfr = *(const short8*)&Wb[(size_t)v * Dd + k + quad * 8];
        #pragma unroll
        for (int rt = 0; rt < 4; ++rt)
          acc[ct][rt] = __builtin_amdgcn_mfma_f32_16x16x32_bf16(afr[rt], bfr, acc[ct][rt], 0, 0, 0);
      }
    }
    #pragma unroll
    for (int ct = 0; ct < 4; ++ct) {
      float bv = bias[vbase + ct * 16 + ln15];
      #pragma unroll
      for (int rt = 0; rt < 4; ++rt)
        #pragma unroll
        for (int r = 0; r < 4; ++r)
          S[rt][r] += __expf(acc[ct][rt][r] + bv);   // |logit| ~ 3: no max needed
    }
  }
  // reduce over the 16 column-lanes (low 4 lane bits)
  #pragma unroll
  for (int off = 1; off < 16; off <<= 1)
    #pragma unroll
    for (int rt = 0; rt < 4; ++rt)
      #pragma unroll
      for (int r = 0; r < 4; ++r)
        S[rt][r] += __shfl_xor(S[rt][r], off, 64);
  if (ln15 == 0) {
    #pragma unroll
    for (int rt = 0; rt < 4; ++rt)
      #pragma unroll
      for (int r = 0; r < 4; ++r)
        atomicAdd(&Ssum[row0 + rt * 16 + quad * 4 + r], S[rt][r]);
  }
  (void)w;
}

// ---- selected-column logits (blank + 30 beams), fp32 ----
// grid: BT/16 blocks, 256 threads. thread = (sel lane 0..31, bt-pair 0..7).
__global__ __launch_bounds__(256) void kB(const float* __restrict__ x,
                                          const float* __restrict__ W,
                                          const float* __restrict__ bias,
                                          const float* __restrict__ Ssum,
                                          const int* __restrict__ beam,
                                          const int* __restrict__ blankp,
                                          float* __restrict__ logp_sel,
                                          int CB) {
  __shared__ float Wlds[31 * 516];
  __shared__ int   selv[32];
  __shared__ float biasv[32];
  const int tid = threadIdx.x;
  const int btbase = blockIdx.x * 16;
  const int b = btbase >> 9;          // 16 | 512 so whole block is one b
  if (tid < 31) {
    int v = (tid == 0) ? *blankp : beam[b * CB + tid - 1];
    selv[tid] = v;
    biasv[tid] = bias[v];
  }
  __syncthreads();
  for (int i = tid; i < 31 * 128; i += 256) {
    int s = i >> 7, c4 = i & 127;
    float4 w4 = *(const float4*)&W[(size_t)selv[s] * Dd + c4 * 4];
    *(float4*)&Wlds[s * 516 + c4 * 4] = w4;
  }
  __syncthreads();
  const int sx = tid & 31, pair = tid >> 5;
  const int kk = (sx < 31) ? sx : 30;
  const int bt0 = btbase + pair * 2, bt1 = bt0 + 1;
  const float4* x40 = (const float4*)&x[(size_t)bt0 * Dd];
  const float4* x41 = (const float4*)&x[(size_t)bt1 * Dd];
  float a0 = 0.f, a1 = 0.f;
  for (int i4 = 0; i4 < 128; ++i4) {
    float4 w4 = *(const float4*)&Wlds[kk * 516 + i4 * 4];
    float4 u = x40[i4];
    float4 v = x41[i4];
    a0 += w4.x * u.x + w4.y * u.y + w4.z * u.z + w4.w * u.w;
    a1 += w4.x * v.x + w4.y * v.y + w4.z * v.z + w4.w * v.w;
  }
  if (sx < 31) {
    float l0 = __logf(Ssum[bt0]);
    float l1 = __logf(Ssum[bt1]);
    logp_sel[(size_t)bt0 * 31 + sx] = a0 + biasv[sx] - l0;
    logp_sel[(size_t)bt1 * 31 + sx] = a1 + biasv[sx] - l1;
  }
}

// ---- CTC DP + output assembly. grid: B blocks x 64 threads (1 wave) ----
__global__ __launch_bounds__(64) void kC(const float* __restrict__ lp_all,
                                         const int* __restrict__ xl,
                                         const int* __restrict__ beam,
                                         const int* __restrict__ blankp,
                                         const int* __restrict__ eosp,
                                         float* __restrict__ out,
                                         int Ly, int CB) {
  __shared__ float lastP1[Tt];
  __shared__ float blankLp[Tt];
  const int b = blockIdx.x, lane = threadIdx.x;
  const float* lp = lp_all + (size_t)b * Tt * 31;

  // blank log-probs + prefix sum (cumsum over t)
  float vloc[8];
  float run = 0.f;
  #pragma unroll
  for (int u = 0; u < 8; ++u) {
    int t = lane * 8 + u;
    float bl = lp[t * 31];
    blankLp[t] = bl;
    run += bl;
    vloc[u] = run;
  }
  float inc = run;
  #pragma unroll
  for (int off = 1; off < 64; off <<= 1) {
    float o = __shfl_up(inc, off, 64);
    if (lane >= off) inc += o;
  }
  float excl = inc - run;
  #pragma unroll
  for (int u = 0; u < 8; ++u) lastP1[lane * 8 + u] = vloc[u] + excl;
  __syncthreads();

  const int xlb = xl[b];
  const int kk = (lane < CB) ? lane : (CB - 1);
  float Pn = LOGZERO, Pb = LOGZERO;
  float mrun = -3.0e38f, srun = 0.0f;
  int start = (Ly < Tt - 1) ? Ly : (Tt - 1);
  if (start == 0) {
    Pn = lp[1 + kk];
    float vv = (0 < xlb) ? lgadd(Pn, Pb) : LOGZERO;
    float nm = fmaxf(mrun, vv);
    srun = srun * __expf(mrun - nm) + __expf(vv - nm);
    mrun = nm;
  }
  int t0 = (start > 1) ? start : 1;
  for (int t = t0; t < Tt; ++t) {
    float xn = lp[t * 31 + 1 + kk];
    float xb = blankLp[t];
    float pref = lastP1[t - 1];   // lastPsum == lastP1 bit-exactly (logaddexp w/ LOGZERO)
    float Pn2 = lgadd(Pn, pref) + xn;
    float Pb2 = lgadd(Pn, Pb) + xb;
    Pn = Pn2; Pb = Pb2;
    float vv = (t < xlb) ? lgadd(Pn, Pb) : LOGZERO;
    float nm = fmaxf(mrun, vv);
    srun = srun * __expf(mrun - nm) + __expf(vv - nm);
    mrun = nm;
  }
  float curP = mrun + __logf(srun);

  float* orow = out + (size_t)b * Vv;
  for (int i = lane; i < Vv; i += 64) orow[i] = LOGZERO;
  __syncthreads();
  if (lane < CB) orow[beam[b * CB + lane]] = curP;
  __syncthreads();
  if (lane == 0) {
    float eosv = (xlb >= 1) ? lastP1[xlb - 1] : 0.0f;  // sum of one-hot row; 0.0 if empty
    orow[*eosp] = eosv;
    orow[*blankp] = LOGZERO;
  }
}

extern "C" void kernel_launch(void* const* d_in, const int* in_sizes, int n_in,
                              void* d_out, int out_size, void* d_ws, size_t ws_size,
                              hipStream_t stream) {
  (void)n_in; (void)out_size; (void)ws_size;
  const float* x    = (const float*)d_in[0];
  const float* W    = (const float*)d_in[1];
  const float* bias = (const float*)d_in[2];
  const int* xl     = (const int*)d_in[3];
  const int* beam   = (const int*)d_in[5];
  const int* blankp = (const int*)d_in[6];
  const int* eosp   = (const int*)d_in[7];
  const int Ly = in_sizes[4] / Bb;
  const int CB = in_sizes[5] / Bb;

  float* Ssum      = (float*)d_ws;                               // BT floats  (64 KB)
  float* logp_sel  = (float*)((char*)d_ws + 65536);              // BT*31 floats (~1.94 MB)
  unsigned short* Wbf = (unsigned short*)((char*)d_ws + 2097152); // V*D bf16 (4 MB)
  float* outf = (float*)d_out;

  hipMemsetAsync(Ssum, 0, BT * sizeof(float), stream);
  kWconv<<<(Vv * Dd) / 1024, 256, 0, stream>>>(W, Wbf);
  kA<<<(BT / 64) * 2, 256, 0, stream>>>(x, Wbf, bias, Ssum);
  kB<<<BT / 16, 256, 0, stream>>>(x, W, bias, Ssum, beam, blankp, logp_sel, CB);
  kC<<<Bb, 64, 0, stream>>>(logp_sel, xl, beam, blankp, eosp, outf, Ly, CB);
}